// Round 3
// baseline (509.207 us; speedup 1.0000x reference)
//
#include <hip/hip_runtime.h>

#define BT    8192
#define DIM   512
#define NLAT  10000
#define LPAD2 10240   // 80 * 128
#define NG    20

typedef short bf16x8 __attribute__((ext_vector_type(8)));
typedef float f32x4  __attribute__((ext_vector_type(4)));
typedef unsigned short u16;
typedef u16 u16x8 __attribute__((ext_vector_type(8)));

static __device__ __forceinline__ u16 f2bf(float f) {
    union { float f; unsigned u; } v; v.f = f;
    unsigned r = v.u + 0x7FFF + ((v.u >> 16) & 1);   // RNE
    return (u16)(r >> 16);
}

static __device__ __forceinline__ void gload16(const void* g, void* l) {
    __builtin_amdgcn_global_load_lds(
        (const __attribute__((address_space(1))) unsigned int*)g,
        (__attribute__((address_space(3))) unsigned int*)l,
        16, 0, 0);
}

// ---------------- lang_emb = tanh(sum_valid char_table[x]); also bf16 copy ----------
__global__ __launch_bounds__(512) void lang_kernel(
        const int* __restrict__ x, const float* __restrict__ ct,
        float* __restrict__ lang, u16* __restrict__ qb) {
    const int tok = blockIdx.x;
    const int d   = threadIdx.x;
    const int* xr = x + tok * NG;
    float s = 0.f;
    #pragma unroll
    for (int j = 0; j < NG; ++j) {
        int c = xr[j];                 // wave-uniform -> s_load
        if (c != 1) s += ct[c * DIM + d];
    }
    float t = tanhf(s);
    lang[(long)tok * DIM + d] = t;
    qb[(long)tok * DIM + d]   = f2bf(t);
}

// -------- latent_mat f32 -> kvg bf16 [LPAD2][DIM] and latT bf16 [DIM][LPAD2] --------
__global__ __launch_bounds__(256) void conv_kernel(
        const float* __restrict__ lm, u16* __restrict__ kvg, u16* __restrict__ latT) {
    __shared__ u16 tile[64][514];
    const int lb = blockIdx.x * 64;
    const int t  = threadIdx.x;

    #pragma unroll 4
    for (int i = 0; i < 16; ++i) {
        int ch  = t + i * 256;
        int r   = ch >> 6;
        int c8  = ch & 63;
        int row = lb + r;
        u16x8 v = {0,0,0,0,0,0,0,0};
        if (row < NLAT) {
            const float* src = lm + (long)row * DIM + c8 * 8;
            float4 a = *(const float4*)src;
            float4 b = *(const float4*)(src + 4);
            v[0]=f2bf(a.x); v[1]=f2bf(a.y); v[2]=f2bf(a.z); v[3]=f2bf(a.w);
            v[4]=f2bf(b.x); v[5]=f2bf(b.y); v[6]=f2bf(b.z); v[7]=f2bf(b.w);
        }
        *(u16x8*)(kvg + (long)row * DIM + c8 * 8) = v;
        #pragma unroll
        for (int j = 0; j < 8; ++j) tile[r][c8 * 8 + j] = v[j];
    }
    __syncthreads();
    #pragma unroll 4
    for (int i = 0; i < 16; ++i) {
        int ch = t + i * 256;
        int d  = ch >> 3;
        int c8 = ch & 7;
        u16x8 v;
        #pragma unroll
        for (int j = 0; j < 8; ++j) v[j] = tile[c8 * 8 + j][d];
        *(u16x8*)(latT + (long)d * LPAD2 + lb + c8 * 8) = v;
    }
}

// -------- GEMM1: P = exp(Q @ kvg^T) masked, bf16; rowsum += row partials ------------
// C[m][n] = sum_k Q[m][k] * kvg[n][k]   (NT), M=8192, N=np*128, K=512
__global__ __launch_bounds__(256) void gemm1_kernel(
        const u16* __restrict__ Q, const u16* __restrict__ L,
        u16* __restrict__ P, float* __restrict__ rowsum,
        int n0_global, int npanels, int pstride) {
    __shared__ u16 AB[2 * 128 * 64];        // As | Bs ; reused as 128x128 P-tile
    u16* As = AB;
    u16* Bs = AB + 128 * 64;

    const int nwg = 64 * npanels;
    const int cpx = nwg >> 3;
    const int bid = blockIdx.x;
    const int wg  = (bid & 7) * cpx + (bid >> 3);
    const int mb  = wg / npanels, nb = wg % npanels;
    const long m0    = (long)mb * 128;
    const int  ncol0 = n0_global + nb * 128;

    const u16* Ag = Q + m0 * DIM;
    const u16* Bg = L + (long)ncol0 * DIM;

    const int t = threadIdx.x, lane = t & 63, w = t >> 6;
    const int wm = w >> 1, wn = w & 1;
    const int g = lane >> 4, lr = lane & 15;
    const int r8 = lane >> 3, c3 = lane & 7;
    const int scol = (c3 ^ r8) * 8;          // pre-swizzled source chunk

    f32x4 acc[4][4];
    #pragma unroll
    for (int m = 0; m < 4; ++m)
        #pragma unroll
        for (int n = 0; n < 4; ++n) acc[m][n] = f32x4{0.f,0.f,0.f,0.f};

    #pragma unroll 1
    for (int kt = 0; kt < DIM / 64; ++kt) {
        const int k0 = kt * 64;
        #pragma unroll
        for (int i = 0; i < 4; ++i) {
            int c = i * 4 + w;
            gload16(Ag + (long)(c * 8 + r8) * DIM + k0 + scol, &As[c * 512]);
            gload16(Bg + (long)(c * 8 + r8) * DIM + k0 + scol, &Bs[c * 512]);
        }
        __syncthreads();
        #pragma unroll
        for (int kc = 0; kc < 2; ++kc) {
            const int xs = ((kc * 4 + g) ^ (lr & 7)) * 8;
            bf16x8 af[4], bfr[4];
            #pragma unroll
            for (int m = 0; m < 4; ++m)
                af[m] = *(const bf16x8*)&As[(wm * 64 + m * 16 + lr) * 64 + xs];
            #pragma unroll
            for (int n = 0; n < 4; ++n)
                bfr[n] = *(const bf16x8*)&Bs[(wn * 64 + n * 16 + lr) * 64 + xs];
            #pragma unroll
            for (int m = 0; m < 4; ++m)
                #pragma unroll
                for (int n = 0; n < 4; ++n)
                    acc[m][n] = __builtin_amdgcn_mfma_f32_16x16x32_bf16(af[m], bfr[n], acc[m][n], 0, 0, 0);
        }
        __syncthreads();
    }

    // ---- epilogue: exp + mask (in place) ----
    #pragma unroll
    for (int m = 0; m < 4; ++m)
        #pragma unroll
        for (int n = 0; n < 4; ++n) {
            const int col = ncol0 + wn * 64 + n * 16 + lr;
            const bool ok = (col < NLAT);
            #pragma unroll
            for (int r = 0; r < 4; ++r)
                acc[m][n][r] = ok ? __expf(acc[m][n][r]) : 0.f;
        }

    // ---- rowsum partials: shfl-reduce over 16 cols, one atomic per (row, wave) ----
    #pragma unroll
    for (int m = 0; m < 4; ++m) {
        float sv[4] = {0.f, 0.f, 0.f, 0.f};
        #pragma unroll
        for (int n = 0; n < 4; ++n)
            #pragma unroll
            for (int r = 0; r < 4; ++r) sv[r] += acc[m][n][r];
        #pragma unroll
        for (int r = 0; r < 4; ++r) {
            float s = sv[r];
            s += __shfl_xor(s, 1); s += __shfl_xor(s, 2);
            s += __shfl_xor(s, 4); s += __shfl_xor(s, 8);
            if (lr == 0)
                atomicAdd(&rowsum[m0 + wm * 64 + m * 16 + g * 4 + r], s);
        }
    }

    // ---- pack bf16 pairs into LDS (row-XOR swizzled), then 16B coalesced stores ----
    unsigned int* S32 = (unsigned int*)AB;
    #pragma unroll
    for (int m = 0; m < 4; ++m)
        #pragma unroll
        for (int n = 0; n < 4; ++n)
            #pragma unroll
            for (int r = 0; r < 4; ++r) {
                float v  = acc[m][n][r];
                float pv = __shfl_xor(v, 1);
                if (!(lr & 1)) {
                    unsigned int pk = (unsigned int)f2bf(v) | ((unsigned int)f2bf(pv) << 16);
                    const int row = wm * 64 + m * 16 + g * 4 + r;
                    const int dw  = wn * 32 + n * 8 + (lr >> 1);
                    S32[row * 64 + (dw ^ ((row & 7) << 3))] = pk;
                }
            }
    __syncthreads();
    #pragma unroll
    for (int it = 0; it < 8; ++it) {
        const int flat = t + it * 256;          // 0..2047
        const int row = flat >> 4, ck = flat & 15;
        u16x8 v = *(const u16x8*)&AB[row * 128 + ((ck ^ ((row & 7) << 1)) * 8)];
        *(u16x8*)(P + (m0 + row) * (long)pstride + nb * 128 + ck * 8) = v;
    }
}

// -------- GEMM2: buf = P @ latT^T (NT), BM=128 BN=256 BK=64, split-K ----------------
__global__ __launch_bounds__(256) void gemm2_kernel(
        const u16* __restrict__ P, const u16* __restrict__ LT,
        float* __restrict__ out, float* __restrict__ part0,
        int pstride, int np, int n0_global, int splitk, int accum) {
    __shared__ u16 As[128 * 64];
    __shared__ u16 Bs[256 * 64];

    const int nwg = 64 * 2 * splitk;
    const int cpx = nwg >> 3;
    const int bid = blockIdx.x;
    const int wg  = (bid & 7) * cpx + (bid >> 3);
    const int per = 2 * splitk;
    const int mb  = wg / per;
    const int rst = wg % per;
    const int nb  = rst / splitk;
    const int s   = rst % splitk;

    const long m0    = (long)mb * 128;
    const int  nbase = nb * 256;

    const int q = np / splitk, rr = np % splitk;
    const int pan  = q + (s < rr ? 1 : 0);
    const int poff = s * q + (s < rr ? s : rr);

    const int t = threadIdx.x, lane = t & 63, w = t >> 6;
    const int g = lane >> 4, lr = lane & 15;
    const int r8 = lane >> 3, c3 = lane & 7;
    const int scol = (c3 ^ r8) * 8;

    float* buf = (s == 0) ? out : part0;

    f32x4 acc[8][4];
    #pragma unroll
    for (int m = 0; m < 8; ++m)
        #pragma unroll
        for (int n = 0; n < 4; ++n) acc[m][n] = f32x4{0.f,0.f,0.f,0.f};

    const int nk = pan * 2;
    #pragma unroll 1
    for (int kt = 0; kt < nk; ++kt) {
        const int kloc = poff * 128 + kt * 64;
        #pragma unroll
        for (int i = 0; i < 4; ++i) {
            int c = i * 4 + w;                       // 0..15 (A rows c*8..+7)
            gload16(P + (m0 + c * 8 + r8) * (long)pstride + kloc + scol, &As[c * 512]);
        }
        #pragma unroll
        for (int i = 0; i < 8; ++i) {
            int c = i * 4 + w;                       // 0..31 (B rows c*8..+7)
            gload16(LT + (long)(nbase + c * 8 + r8) * LPAD2 + n0_global + kloc + scol,
                    &Bs[c * 512]);
        }
        __syncthreads();
        #pragma unroll
        for (int kc = 0; kc < 2; ++kc) {
            const int xs = ((kc * 4 + g) ^ (lr & 7)) * 8;
            bf16x8 af[8], bfr[4];
            #pragma unroll
            for (int mf = 0; mf < 8; ++mf)
                af[mf] = *(const bf16x8*)&As[(mf * 16 + lr) * 64 + xs];
            #pragma unroll
            for (int nf = 0; nf < 4; ++nf)
                bfr[nf] = *(const bf16x8*)&Bs[(w * 64 + nf * 16 + lr) * 64 + xs];
            #pragma unroll
            for (int mf = 0; mf < 8; ++mf)
                #pragma unroll
                for (int nf = 0; nf < 4; ++nf)
                    acc[mf][nf] = __builtin_amdgcn_mfma_f32_16x16x32_bf16(af[mf], bfr[nf], acc[mf][nf], 0, 0, 0);
        }
        __syncthreads();
    }

    #pragma unroll
    for (int mf = 0; mf < 8; ++mf)
        #pragma unroll
        for (int nf = 0; nf < 4; ++nf) {
            const int col = nbase + w * 64 + nf * 16 + lr;
            #pragma unroll
            for (int r = 0; r < 4; ++r) {
                const long row = m0 + mf * 16 + g * 4 + r;
                float v = acc[mf][nf][r];
                if (accum) v += buf[row * DIM + col];
                buf[row * DIM + col] = v;
            }
        }
}

// -------- final: out = (out [+part0])/rowsum + lang; first-token override -----------
__global__ __launch_bounds__(256) void final_kernel(
        float* __restrict__ out, const float* __restrict__ part0,
        const float* __restrict__ lang, const float* __restrict__ rowsum,
        const int* __restrict__ x, const float* __restrict__ ct, int nparts) {
    const int tok   = blockIdx.x;
    const float inv = 1.f / rowsum[tok];
    const int first = x[tok * NG];
    #pragma unroll
    for (int i = 0; i < 2; ++i) {
        const int col = threadIdx.x + i * 256;
        float v = out[(long)tok * DIM + col];
        if (nparts > 1) v += part0[(long)tok * DIM + col];
        v = v * inv + lang[(long)tok * DIM + col];
        if (first < 4) v = ct[first * DIM + col];
        out[(long)tok * DIM + col] = v;
    }
}

extern "C" void kernel_launch(void* const* d_in, const int* in_sizes, int n_in,
                              void* d_out, int out_size, void* d_ws, size_t ws_size,
                              hipStream_t stream) {
    const int*   x  = (const int*)d_in[0];
    const float* ct = (const float*)d_in[1];
    const float* lm = (const float*)d_in[2];
    float* out = (float*)d_out;

    char* ws = (char*)d_ws;
    size_t off = 0;
    u16*   qb   = (u16*)(ws + off);   off += (size_t)BT * DIM * 2;      // 8 MB
    float* lang = (float*)(ws + off); off += (size_t)BT * DIM * 4;      // 16 MB
    u16*   kvg  = (u16*)(ws + off);   off += (size_t)LPAD2 * DIM * 2;   // 10 MB
    u16*   latT = (u16*)(ws + off);   off += (size_t)DIM * LPAD2 * 2;   // 10 MB
    float* rowsum = (float*)(ws + off); off += (size_t)BT * 4;          // 32 KB
    u16*   P    = (u16*)(ws + off);
    const size_t fixed = off;

    const int panels_total = LPAD2 / 128;                  // 80
    const size_t pfull = (size_t)BT * LPAD2 * 2;           // 160 MiB
    const size_t partb = (size_t)BT * DIM * 4;             // 16 MiB

    int splitk = 1, ppc = panels_total;
    float* part0 = out;   // dummy when unused
    if (ws_size >= fixed + pfull + partb) {
        splitk = 2;
        part0 = (float*)(ws + fixed + pfull);
    } else if (ws_size >= fixed + pfull) {
        splitk = 1;
    } else {
        size_t avail = (ws_size > fixed) ? (ws_size - fixed) : 0;
        size_t p = avail / ((size_t)BT * 128 * 2);
        ppc = (int)(p < 1 ? 1 : (p > (size_t)panels_total ? (size_t)panels_total : p));
    }
    const int pstride = ppc * 128;

    hipMemsetAsync(rowsum, 0, (size_t)BT * 4, stream);
    lang_kernel<<<BT, 512, 0, stream>>>(x, ct, lang, qb);
    conv_kernel<<<LPAD2 / 64, 256, 0, stream>>>(lm, kvg, latT);

    int chunk = 0;
    for (int cs = 0; cs < panels_total; cs += ppc, ++chunk) {
        const int np = (panels_total - cs < ppc) ? (panels_total - cs) : ppc;
        gemm1_kernel<<<64 * np, 256, 0, stream>>>(qb, kvg, P, rowsum,
                                                  cs * 128, np, pstride);
        gemm2_kernel<<<64 * 2 * splitk, 256, 0, stream>>>(P, latT, out, part0,
                                                          pstride, np, cs * 128,
                                                          splitk, chunk > 0 ? 1 : 0);
    }
    final_kernel<<<BT, 256, 0, stream>>>(out, part0, lang, rowsum, x, ct, splitk);
}